// Round 5
// baseline (479.708 us; speedup 1.0000x reference)
//
#include <hip/hip_runtime.h>
#include <math.h>

// ---------------------------------------------------------------------------
// SpectralConv3d + Chebyshev-Fourier correction, fp32, pruned separable DFTs.
// B=4, C=O=32, H=W=D=64. Modes: kx in {0..11, 52..63} (24), ky same (24),
// kz in {0..11} (12).
// out = (1/64^3) * Re[ sum F[kx,ky,kz] * w^(kx h + ky w + kz d) * c_kz ]
//       + corr_scale * corr[b,o,d],  c_0 = 1, c_kz = 2 (kz>=1).
//
// R1: DFT symmetries (d<->64-d, conjugate output pairs, h<->64-h, E/O).
// R2: E/O pairing along the summation axes everywhere.
// R3: twiddle recurrence replaced LDS twiddle gathers.
// R4: literal-twiddle z-stage (wave-uniform kz triplet), but [d][w] layout
//     forced scalar b32 reads -> LDS-pipe bound (516 LDS instrs/block).
// R5 (this round): every LDS access b128.
//  - z-stage: xt[w][68] row-major, lane=w reads its row as 16 ds_read_b128
//    (rolling quad window, compile-time mirror indices), literal twiddles.
//  - dual-copy z1: zA[kz][w] + zB[kz][64-w]; y-stage reads (w,w+1) via one
//    b128 from zA and their mirrors via one b128 from zB: 64 -> ~19 instrs.
//  - k_fwd_x: transposed dual-copy staging (s2A/s2B[kz][h]) + same y-loop.
// ---------------------------------------------------------------------------

#define CMUL_STEP(t, u) do { float _nx = (t).x*(u).x - (t).y*(u).y; \
    (t).y = (t).x*(u).y + (t).y*(u).x; (t).x = _nx; } while (0)

// cos(2*pi*m/64), m = 0..63 (sin(m) = cos((m+48)&63))
constexpr float TW_C[64] = {
     1.000000000000000f,  0.995184726672197f,  0.980785280403230f,  0.956940335732209f,
     0.923879532511287f,  0.881921264348355f,  0.831469612302545f,  0.773010453362737f,
     0.707106781186548f,  0.634393284163645f,  0.555570233019602f,  0.471396736825998f,
     0.382683432365090f,  0.290284677254462f,  0.195090322016128f,  0.098017140329561f,
     0.000000000000000f, -0.098017140329561f, -0.195090322016128f, -0.290284677254462f,
    -0.382683432365090f, -0.471396736825998f, -0.555570233019602f, -0.634393284163645f,
    -0.707106781186548f, -0.773010453362737f, -0.831469612302545f, -0.881921264348355f,
    -0.923879532511287f, -0.956940335732209f, -0.980785280403230f, -0.995184726672197f,
    -1.000000000000000f, -0.995184726672197f, -0.980785280403230f, -0.956940335732209f,
    -0.923879532511287f, -0.881921264348355f, -0.831469612302545f, -0.773010453362737f,
    -0.707106781186548f, -0.634393284163645f, -0.555570233019602f, -0.471396736825998f,
    -0.382683432365090f, -0.290284677254462f, -0.195090322016128f, -0.098017140329561f,
     0.000000000000000f,  0.098017140329561f,  0.195090322016128f,  0.290284677254462f,
     0.382683432365090f,  0.471396736825998f,  0.555570233019602f,  0.634393284163645f,
     0.707106781186548f,  0.773010453362737f,  0.831469612302545f,  0.881921264348355f,
     0.923879532511287f,  0.956940335732209f,  0.980785280403230f,  0.995184726672197f
};
constexpr float twc(int m) { return TW_C[m & 63]; }
constexpr float tws(int m) { return TW_C[(m + 48) & 63]; }

static __device__ __forceinline__ void fill_tw(float2* tw, int tid, int nthr) {
    // tw[m] = (cos(2 pi m / 64), sin(2 pi m / 64))
    for (int m = tid; m < 64; m += nthr) {
        float s, c;
        sincosf((float)m * 0.09817477042468103f, &s, &c);
        tw[m] = make_float2(c, s);
    }
}

// ---------------------------------------------------------------------------
// Shared y-stage inner loop: forward DFT over 64 samples -> conjugate output
// pair (k=ap, k=64-ap) with summation pairing w<->64-w via dual-copy LDS.
// Ar[w] = z[w] (w=0..63), Br[w] = z[64-w] (w=1..63). All b128 reads.
// ---------------------------------------------------------------------------
static __device__ __forceinline__ void ystage_pair(const float2* __restrict__ Ar,
                                                   const float2* __restrict__ Br,
                                                   int ap, float2& A, float2& Bc) {
    const float2 zw0 = Ar[0];
    const float2 zw32 = Ar[32];
    const float sg = (ap & 1) ? -1.f : 1.f;
    A.x = zw0.x + sg * zw32.x;  A.y = zw0.y + sg * zw32.y;
    Bc = A;
    float s_, c_;
    sincosf((float)ap * 0.09817477042468103f, &s_, &c_);
    const float2 u = make_float2(c_, s_);
    float2 t = u;                        // t = W^ap (w = 1)
    {   // w = 1
        float2 za = Ar[1], zb = Br[1];
        float Ex = za.x + zb.x, Ey = za.y + zb.y;
        float Ox = za.x - zb.x, Oy = za.y - zb.y;
        A.x  += t.x * Ex + t.y * Oy;  A.y  += t.x * Ey - t.y * Ox;
        Bc.x += t.x * Ex - t.y * Oy;  Bc.y += t.x * Ey + t.y * Ox;
    }
    #pragma unroll
    for (int w = 2; w < 32; w += 2) {
        CMUL_STEP(t, u);                       // t = W^{ap*w}
        const float4 a4 = *(const float4*)(Ar + w);  // z[w], z[w+1]
        const float4 b4 = *(const float4*)(Br + w);  // z[64-w], z[63-w]
        {
            float Ex = a4.x + b4.x, Ey = a4.y + b4.y;
            float Ox = a4.x - b4.x, Oy = a4.y - b4.y;
            A.x  += t.x * Ex + t.y * Oy;  A.y  += t.x * Ey - t.y * Ox;
            Bc.x += t.x * Ex - t.y * Oy;  Bc.y += t.x * Ey + t.y * Ox;
        }
        CMUL_STEP(t, u);                       // t = W^{ap*(w+1)}
        {
            float Ex = a4.z + b4.z, Ey = a4.w + b4.w;
            float Ox = a4.z - b4.z, Oy = a4.w - b4.w;
            A.x  += t.x * Ex + t.y * Oy;  A.y  += t.x * Ey - t.y * Ox;
            Bc.x += t.x * Ex - t.y * Oy;  Bc.y += t.x * Ey + t.y * Ox;
        }
    }
}

// ---------------------------------------------------------------------------
// Kernel 1: fused forward DFT along D (64->12) and W (64->24).
// grid = B*C*H = 8192 blocks, 256 threads. X2[(bc*64+h)*288 + a*12 + kz]
// z-stage: wave q owns kz {3q..3q+2}, lane = w, b128 row reads, literal tw.
// ---------------------------------------------------------------------------
template<int KZ0>
static __device__ __forceinline__ void zstage_wave(const float* __restrict__ row,
                                                   float2* __restrict__ zA,
                                                   float2* __restrict__ zB,
                                                   int w) {
    float a0x, a0y = 0.f, a1x, a1y = 0.f, a2x, a2y = 0.f;
#define ACCD(dd, xa, xb) do { \
    const float e_ = (xa) + (xb), o_ = (xa) - (xb); \
    a0x += e_ * twc((KZ0    ) * (dd));  a0y -= o_ * tws((KZ0    ) * (dd)); \
    a1x += e_ * twc((KZ0 + 1) * (dd));  a1y -= o_ * tws((KZ0 + 1) * (dd)); \
    a2x += e_ * twc((KZ0 + 2) * (dd));  a2y -= o_ * tws((KZ0 + 2) * (dd)); } while (0)
    float4 qa  = *(const float4*)(row + 0);    // d 0..3
    float4 qm1 = *(const float4*)(row + 60);   // 60..63
    float4 qm0 = *(const float4*)(row + 56);   // 56..59
    const float x0v = qa.x;
    a0x = x0v; a1x = x0v; a2x = x0v;
    ACCD(1, qa.y, qm1.w);
    ACCD(2, qa.z, qm1.z);
    ACCD(3, qa.w, qm1.y);
    float mnext = qm1.x;                       // 60 = mirror of d=4
    qa = *(const float4*)(row + 4);            // 4..7
    ACCD(4, qa.x, mnext);
    ACCD(5, qa.y, qm0.w);
    ACCD(6, qa.z, qm0.z);
    ACCD(7, qa.w, qm0.y);
    mnext = qm0.x;                             // 56 = mirror of d=8
    qm0 = *(const float4*)(row + 52);          // 52..55
    qa  = *(const float4*)(row + 8);           // 8..11
    ACCD(8,  qa.x, mnext);
    ACCD(9,  qa.y, qm0.w);
    ACCD(10, qa.z, qm0.z);
    ACCD(11, qa.w, qm0.y);
    mnext = qm0.x;                             // 52
    qm0 = *(const float4*)(row + 48);
    qa  = *(const float4*)(row + 12);
    ACCD(12, qa.x, mnext);
    ACCD(13, qa.y, qm0.w);
    ACCD(14, qa.z, qm0.z);
    ACCD(15, qa.w, qm0.y);
    mnext = qm0.x;                             // 48
    qm0 = *(const float4*)(row + 44);
    qa  = *(const float4*)(row + 16);
    ACCD(16, qa.x, mnext);
    ACCD(17, qa.y, qm0.w);
    ACCD(18, qa.z, qm0.z);
    ACCD(19, qa.w, qm0.y);
    mnext = qm0.x;                             // 44
    qm0 = *(const float4*)(row + 40);
    qa  = *(const float4*)(row + 20);
    ACCD(20, qa.x, mnext);
    ACCD(21, qa.y, qm0.w);
    ACCD(22, qa.z, qm0.z);
    ACCD(23, qa.w, qm0.y);
    mnext = qm0.x;                             // 40
    qm0 = *(const float4*)(row + 36);
    qa  = *(const float4*)(row + 24);
    ACCD(24, qa.x, mnext);
    ACCD(25, qa.y, qm0.w);
    ACCD(26, qa.z, qm0.z);
    ACCD(27, qa.w, qm0.y);
    mnext = qm0.x;                             // 36
    qm0 = *(const float4*)(row + 32);          // 32..35
    qa  = *(const float4*)(row + 28);          // 28..31
    ACCD(28, qa.x, mnext);
    ACCD(29, qa.y, qm0.w);
    ACCD(30, qa.z, qm0.z);
    ACCD(31, qa.w, qm0.y);
    const float x32v = qm0.x;
#undef ACCD
    const float s0 = ((KZ0     & 1)) ? -x32v : x32v;
    const float s1 = (((KZ0+1) & 1)) ? -x32v : x32v;
    a0x += s0; a1x += s1; a2x += s0;
    zA[(KZ0    ) * 66 + w] = make_float2(a0x, a0y);
    zA[(KZ0 + 1) * 66 + w] = make_float2(a1x, a1y);
    zA[(KZ0 + 2) * 66 + w] = make_float2(a2x, a2y);
    const int wm = 64 - w;                     // w=0 -> pad slot 64
    zB[(KZ0    ) * 66 + wm] = make_float2(a0x, a0y);
    zB[(KZ0 + 1) * 66 + wm] = make_float2(a1x, a1y);
    zB[(KZ0 + 2) * 66 + wm] = make_float2(a2x, a2y);
}

__global__ __launch_bounds__(256) void k_fwd_zy(const float* __restrict__ x,
                                                float2* __restrict__ X2) {
    __shared__ __align__(16) float xt[64 * 68];    // [w][d], stride 68 (16B rows)
    __shared__ __align__(16) float2 zA[12 * 66];   // [kz][w]
    __shared__ __align__(16) float2 zB[12 * 66];   // [kz][64-w]
    const int tid = threadIdx.x;
    const int blk = blockIdx.x;          // (b*32+c)*64 + h
    const float4* xrow4 = (const float4*)(x + (size_t)blk * 4096);
    for (int r = 0; r < 4; ++r) {
        int i4 = r * 256 + tid;          // 1024 float4 = 4096 floats
        int w = i4 >> 4, d4 = (i4 & 15) << 2;
        *(float4*)&xt[w * 68 + d4] = xrow4[i4];
    }
    __syncthreads();
    {
        const int q = tid >> 6, w = tid & 63;
        const float* row = &xt[w * 68];
        switch (q) {
            case 0: zstage_wave<0>(row, zA, zB, w); break;
            case 1: zstage_wave<3>(row, zA, zB, w); break;
            case 2: zstage_wave<6>(row, zA, zB, w); break;
            default: zstage_wave<9>(row, zA, zB, w); break;
        }
    }
    __syncthreads();
    float2* xout = X2 + (size_t)blk * 288;
    if (tid < 156) {                     // 13 ap values * 12 kz
        const int ap = tid / 12, kz = tid - (tid / 12) * 12;
        float2 A, Bc;
        ystage_pair(&zA[kz * 66], &zB[kz * 66], ap, A, Bc);
        if (ap <= 11) xout[ap * 12 + kz] = A;
        if (ap >= 1)  xout[(24 - ap) * 12 + kz] = Bc;
    }
}

// ---------------------------------------------------------------------------
// Kernel 2: forward DFT along H (64->24), dual-copy transposed staging +
// shared b128 y-loop. grid = B*C*24 = 3072, 256 threads.
// X3[bc*6912 + ax*288 + ay*12 + kz]
// ---------------------------------------------------------------------------
__global__ __launch_bounds__(256) void k_fwd_x(const float2* __restrict__ X2,
                                               float2* __restrict__ X3) {
    __shared__ __align__(16) float2 s2A[12 * 66];  // [kz][h]
    __shared__ __align__(16) float2 s2B[12 * 66];  // [kz][64-h]
    const int tid = threadIdx.x;
    const int blk = blockIdx.x;
    const int ay = blk % 24, bc = blk / 24;
    const float2* src = X2 + (size_t)bc * (64 * 288) + ay * 12;
    for (int i4 = tid; i4 < 384; i4 += 256) {      // 64 rows * 6 float4
        int hh = i4 / 6, c4 = i4 - hh * 6;
        float4 v = ((const float4*)(src + (size_t)hh * 288))[c4];
        int kz = 2 * c4;
        s2A[kz * 66 + hh]            = make_float2(v.x, v.y);
        s2A[(kz + 1) * 66 + hh]      = make_float2(v.z, v.w);
        s2B[kz * 66 + (64 - hh)]     = make_float2(v.x, v.y);
        s2B[(kz + 1) * 66 + (64 - hh)] = make_float2(v.z, v.w);
    }
    __syncthreads();
    float2* dst = X3 + (size_t)bc * 6912 + ay * 12;
    if (tid < 156) {                     // 13 ap values * 12 kz
        const int ap = tid / 12, kz = tid - (tid / 12) * 12;
        float2 A, Bc;
        ystage_pair(&s2A[kz * 66], &s2B[kz * 66], ap, A, Bc);
        if (ap <= 11) dst[ap * 288 + kz] = A;
        if (ap >= 1)  dst[(24 - ap) * 288 + kz] = Bc;
    }
}

// ---------------------------------------------------------------------------
// Kernel 3: mode mixing F[b,o,m] = sum_i X3[b,i,m] * (wre + i wim)[i,o,m].
// grid = 24*24 = 576 blocks (one (ax,ay)), 384 threads = (o,kz).
// Weights streamed from global exactly once in total.
// ---------------------------------------------------------------------------
__global__ __launch_bounds__(384) void k_mix(const float2* __restrict__ X3,
                                             float2* __restrict__ F,
        const float* __restrict__ w1re, const float* __restrict__ w1im,
        const float* __restrict__ w2re, const float* __restrict__ w2im,
        const float* __restrict__ w3re, const float* __restrict__ w3im,
        const float* __restrict__ w4re, const float* __restrict__ w4im) {
    __shared__ float2 xs[128 * 12];      // [b*32+i][kz]
    const int tid = threadIdx.x;
    const int blk = blockIdx.x;
    const int ax = blk / 24, ay = blk % 24;
    const int cx = ax >= 12 ? 1 : 0, cy = ay >= 12 ? 1 : 0;
    const int m1 = ax - cx * 12, m2 = ay - cy * 12;
    const int sel = cx + cy * 2;         // 0:w1 (lo,lo) 1:w2 (hi,lo) 2:w3 (lo,hi) 3:w4
    const float* wre = sel == 0 ? w1re : sel == 1 ? w2re : sel == 2 ? w3re : w4re;
    const float* wim = sel == 0 ? w1im : sel == 1 ? w2im : sel == 2 ? w3im : w4im;
    const size_t moff = (size_t)ax * 288 + (size_t)ay * 12;
    for (int i = tid; i < 1536; i += 384) {
        int bi = i / 12, kz = i - bi * 12;
        xs[i] = X3[(size_t)bi * 6912 + moff + kz];
    }
    __syncthreads();
    const int o = tid / 12, kz = tid - (tid / 12) * 12;
    const int wbase = o * 1728 + m1 * 144 + m2 * 12 + kz;
    float2 A0 = make_float2(0.f, 0.f), A1 = A0, A2 = A0, A3 = A0;
    for (int i = 0; i < 32; ++i) {
        float wr = wre[i * 55296 + wbase];
        float wi = wim[i * 55296 + wbase];
        float2 x0 = xs[i * 12 + kz];
        float2 x1 = xs[(32 + i) * 12 + kz];
        float2 x2 = xs[(64 + i) * 12 + kz];
        float2 x3 = xs[(96 + i) * 12 + kz];
        A0.x += x0.x * wr - x0.y * wi; A0.y += x0.x * wi + x0.y * wr;
        A1.x += x1.x * wr - x1.y * wi; A1.y += x1.x * wi + x1.y * wr;
        A2.x += x2.x * wr - x2.y * wi; A2.y += x2.x * wi + x2.y * wr;
        A3.x += x3.x * wr - x3.y * wi; A3.y += x3.x * wi + x3.y * wr;
    }
    F[(size_t)(0 * 32 + o) * 6912 + moff + kz] = A0;
    F[(size_t)(1 * 32 + o) * 6912 + moff + kz] = A1;
    F[(size_t)(2 * 32 + o) * 6912 + moff + kz] = A2;
    F[(size_t)(3 * 32 + o) * 6912 + moff + kz] = A3;
}

// ---------------------------------------------------------------------------
// Kernel 4: inverse DFT along H (24->64): output pairing h <-> 64-h composed
// with input-mode pairing ax <-> 24-ax; twiddles by recurrence (t <- t*W^hp).
// grid = B*O*24 = 3072, 256 threads. Y1[(bo*64+h)*288 + ay*12 + kz]
// ---------------------------------------------------------------------------
__global__ __launch_bounds__(256) void k_inv_x(const float2* __restrict__ F,
                                               float2* __restrict__ Y1) {
    __shared__ __align__(16) float2 fs[24 * 12];
    __shared__ float2 tw[64];
    const int tid = threadIdx.x;
    const int blk = blockIdx.x;
    const int ay = blk % 24, bo = blk / 24;
    fill_tw(tw, tid, 256);
    const float2* src = F + (size_t)bo * 6912 + ay * 12;
    for (int i4 = tid; i4 < 144; i4 += 256) {      // 24 rows * 6 float4
        int ax = i4 / 6, c4 = i4 - ax * 6;
        ((float4*)&fs[ax * 12])[c4] = ((const float4*)(src + (size_t)ax * 288))[c4];
    }
    __syncthreads();
    float2* dst = Y1 + (size_t)bo * (64 * 288) + ay * 12;
    // hp in 0..32: A -> h=hp; Bc -> h=64-hp (hp in 1..31).
    for (int idx = tid; idx < 396; idx += 256) {   // 33 hp * 12 kz
        int hp = idx / 12, kz = idx - (idx / 12) * 12;
        float2 f0  = fs[kz];
        float2 f12 = fs[12 * 12 + kz];
        float2 t12 = tw[(52 * hp) & 63];
        float2 A, Bc;
        A.x  = f0.x + f12.x * t12.x - f12.y * t12.y;
        A.y  = f0.y + f12.x * t12.y + f12.y * t12.x;
        Bc.x = f0.x + f12.x * t12.x + f12.y * t12.y;
        Bc.y = f0.y + f12.y * t12.x - f12.x * t12.y;
        const float2 u = tw[hp];         // hp <= 32 < 64
        float2 t = u;                    // t(a=1) = W^hp
        for (int a = 1; a <= 11; ++a) {
            float2 fa = fs[a * 12 + kz];
            float2 fb = fs[(24 - a) * 12 + kz];
            float Ex = fa.x + fb.x, Ey = fa.y + fb.y;
            float Ox = fa.x - fb.x, Oy = fa.y - fb.y;
            A.x  += t.x * Ex - t.y * Oy;  A.y  += t.x * Ey + t.y * Ox;
            Bc.x += t.x * Ex + t.y * Oy;  Bc.y += t.x * Ey - t.y * Ox;
            CMUL_STEP(t, u);
        }
        dst[hp * 288 + kz] = A;
        if (hp >= 1 && hp <= 31) dst[(64 - hp) * 288 + kz] = Bc;
    }
}

// ---------------------------------------------------------------------------
// Kernel 5: CFT branch — segment-0 Chebyshev (T0,T1,T2) + 3-freq rDFT over W.
// grid = B*C = 128 blocks, 256 threads = (q=w-group)*64 + d.
// cft[(b*64+d)*576 + c*18 + k*6 + f*2 + {re,im}]
// ---------------------------------------------------------------------------
__global__ __launch_bounds__(256) void k_cft(const float* __restrict__ x,
                                             float* __restrict__ cft) {
    __shared__ float2 tw[64];
    __shared__ float red[3 * 64 * 18];
    const int tid = threadIdx.x;
    const int blk = blockIdx.x;          // b*32 + c
    const int d = tid & 63, q = tid >> 6;
    fill_tw(tw, tid, 256);
    __syncthreads();
    float aR[3][3] = {{0.f}}, aI[3][3] = {{0.f}};
    const float* xb = x + (size_t)blk * 262144;
    for (int wi = 0; wi < 16; ++wi) {
        const int w = q * 16 + wi;
        float c0 = 0.f, c1 = 0.f, c2 = 0.f;
        #pragma unroll
        for (int s = 0; s < 8; ++s) {
            float xv = xb[(size_t)(s * 64 + w) * 64 + d];
            float t = (2.0f * (float)s - 7.0f) * (1.0f / 7.0f);
            c0 += xv;
            c1 += xv * t;
            c2 += xv * (2.0f * t * t - 1.0f);
        }
        c0 *= 0.125f; c1 *= 0.125f; c2 *= 0.125f;
        #pragma unroll
        for (int f = 0; f < 3; ++f) {
            float2 t = tw[(f * w) & 63];
            aR[0][f] += c0 * t.x; aI[0][f] -= c0 * t.y;
            aR[1][f] += c1 * t.x; aI[1][f] -= c1 * t.y;
            aR[2][f] += c2 * t.x; aI[2][f] -= c2 * t.y;
        }
    }
    if (q > 0) {
        float* dst = &red[((q - 1) * 64 + d) * 18];
        #pragma unroll
        for (int k = 0; k < 3; ++k)
            #pragma unroll
            for (int f = 0; f < 3; ++f) {
                dst[k * 6 + f * 2]     = aR[k][f];
                dst[k * 6 + f * 2 + 1] = aI[k][f];
            }
    }
    __syncthreads();
    if (q == 0) {
        #pragma unroll
        for (int qq = 0; qq < 3; ++qq) {
            const float* sr = &red[(qq * 64 + d) * 18];
            #pragma unroll
            for (int k = 0; k < 3; ++k)
                #pragma unroll
                for (int f = 0; f < 3; ++f) {
                    aR[k][f] += sr[k * 6 + f * 2];
                    aI[k][f] += sr[k * 6 + f * 2 + 1];
                }
        }
        const int b = blk >> 5, c = blk & 31;
        float* dst = cft + (size_t)(b * 64 + d) * 576 + c * 18;
        #pragma unroll
        for (int k = 0; k < 3; ++k)
            #pragma unroll
            for (int f = 0; f < 3; ++f) {
                dst[k * 6 + f * 2]     = aR[k][f];
                dst[k * 6 + f * 2 + 1] = aI[k][f];
            }
    }
}

// ---------------------------------------------------------------------------
// Kernel 6: MLP 576->128 (exact GeLU) ->32, pre-scaled by corr_scale.
// grid = B*D = 256 rows, 128 threads. corr[(b*32+o)*64 + d]
// ---------------------------------------------------------------------------
__global__ __launch_bounds__(128) void k_mlp(const float* __restrict__ cft,
                                             const float* __restrict__ w1,
                                             const float* __restrict__ b1,
                                             const float* __restrict__ w2,
                                             const float* __restrict__ b2,
                                             const float* __restrict__ cs,
                                             float* __restrict__ corr) {
    __shared__ float row[576];
    __shared__ float hbuf[128];
    const int n = blockIdx.x;            // b*64 + d
    const int tid = threadIdx.x;
    for (int i = tid; i < 576; i += 128) row[i] = cft[(size_t)n * 576 + i];
    __syncthreads();
    float acc = b1[tid];
    #pragma unroll 8
    for (int k = 0; k < 576; ++k) acc += row[k] * w1[k * 128 + tid];
    hbuf[tid] = 0.5f * acc * (1.0f + erff(acc * 0.70710678118654752f));
    __syncthreads();
    if (tid < 32) {
        float a2 = b2[tid];
        #pragma unroll 8
        for (int k = 0; k < 128; ++k) a2 += hbuf[k] * w2[k * 32 + tid];
        const int b = n >> 6, d = n & 63;
        corr[(b * 32 + tid) * 64 + d] = a2 * cs[0];
    }
}

// ---------------------------------------------------------------------------
// Kernel 7: fused inverse DFT along W (24->64) and D (12->64, c2r with c_kz),
// + correction add. grid = B*O*H = 8192, 256 threads.
// Stage A: mode-pair E/O + twiddle recurrence. Stage B: float4 y2 reads.
// ---------------------------------------------------------------------------
__global__ __launch_bounds__(256) void k_inv_yz(const float2* __restrict__ Y1,
                                                const float* __restrict__ corr,
                                                float* __restrict__ out) {
    __shared__ __align__(16) float2 y1[288];       // [a][kz]
    __shared__ __align__(16) float2 y2[64 * 12];   // [w][kz]
    __shared__ float2 tw[64];
    __shared__ float corrl[64];
    const int tid = threadIdx.x;
    const int blk = blockIdx.x;          // (b*32+o)*64 + h
    const int bo = blk >> 6;
    fill_tw(tw, tid, 256);
    {
        const float4* src4 = (const float4*)(Y1 + (size_t)blk * 288);
        for (int i4 = tid; i4 < 144; i4 += 256) ((float4*)y1)[i4] = src4[i4];
    }
    if (tid < 64) corrl[tid] = corr[bo * 64 + tid];
    __syncthreads();
    // stage A: W inverse, e^{+i 2pi ky w / 64}; thread = (w, kz-triplet).
    {
        const int w = tid >> 2, kz0 = (tid & 3) * 3;
        float2 a0 = make_float2(0.f, 0.f), a1 = a0, a2 = a0;
        {   // a = 0, ky = 0, t = (1,0)
            float2 f0 = y1[kz0], f1 = y1[kz0 + 1], f2 = y1[kz0 + 2];
            a0.x += f0.x; a0.y += f0.y;
            a1.x += f1.x; a1.y += f1.y;
            a2.x += f2.x; a2.y += f2.y;
        }
        {   // a = 12, ky = 52
            float2 t = tw[(52 * w) & 63];
            float2 f0 = y1[144 + kz0], f1 = y1[144 + kz0 + 1], f2 = y1[144 + kz0 + 2];
            a0.x += f0.x * t.x - f0.y * t.y; a0.y += f0.x * t.y + f0.y * t.x;
            a1.x += f1.x * t.x - f1.y * t.y; a1.y += f1.x * t.y + f1.y * t.x;
            a2.x += f2.x * t.x - f2.y * t.y; a2.y += f2.x * t.y + f2.y * t.x;
        }
        const float2 u = tw[w];
        float2 t = u;                    // t(a=1) = W^w
        for (int a = 1; a <= 11; ++a) {
            const float2* fa = &y1[a * 12 + kz0];
            const float2* fb = &y1[(24 - a) * 12 + kz0];
            float2 p0 = fa[0], p1 = fa[1], p2 = fa[2];
            float2 q0 = fb[0], q1 = fb[1], q2 = fb[2];
            float Ex, Ey, Ox, Oy;
            Ex = p0.x + q0.x; Ey = p0.y + q0.y; Ox = p0.x - q0.x; Oy = p0.y - q0.y;
            a0.x += t.x * Ex - t.y * Oy; a0.y += t.x * Ey + t.y * Ox;
            Ex = p1.x + q1.x; Ey = p1.y + q1.y; Ox = p1.x - q1.x; Oy = p1.y - q1.y;
            a1.x += t.x * Ex - t.y * Oy; a1.y += t.x * Ey + t.y * Ox;
            Ex = p2.x + q2.x; Ey = p2.y + q2.y; Ox = p2.x - q2.x; Oy = p2.y - q2.y;
            a2.x += t.x * Ex - t.y * Oy; a2.y += t.x * Ey + t.y * Ox;
            CMUL_STEP(t, u);
        }
        y2[w * 12 + kz0]     = a0;
        y2[w * 12 + kz0 + 1] = a1;
        y2[w * 12 + kz0 + 2] = a2;
    }
    // per-thread fixed d: hoist the 12 D-twiddles (scaled) into registers
    float ctw[12], stw[12];
    const int d = tid & 63;
    #pragma unroll
    for (int kz = 0; kz < 12; ++kz) {
        float2 t = tw[(kz * d) & 63];
        float sc = (kz == 0 ? 1.0f : 2.0f) * (1.0f / 262144.0f);
        ctw[kz] = t.x * sc;
        stw[kz] = t.y * sc;
    }
    __syncthreads();
    const float cv = corrl[d];
    float* orow = out + (size_t)blk * 4096;
    const int wq = tid >> 6;
    for (int r = 0; r < 16; ++r) {
        int w = r * 4 + wq;
        const float4* yv = (const float4*)&y2[w * 12];   // 12 float2 = 6 float4
        float4 p0 = yv[0], p1 = yv[1], p2 = yv[2];
        float4 p3 = yv[3], p4 = yv[4], p5 = yv[5];
        float s = cv;
        s += p0.x * ctw[0]  - p0.y * stw[0];
        s += p0.z * ctw[1]  - p0.w * stw[1];
        s += p1.x * ctw[2]  - p1.y * stw[2];
        s += p1.z * ctw[3]  - p1.w * stw[3];
        s += p2.x * ctw[4]  - p2.y * stw[4];
        s += p2.z * ctw[5]  - p2.w * stw[5];
        s += p3.x * ctw[6]  - p3.y * stw[6];
        s += p3.z * ctw[7]  - p3.w * stw[7];
        s += p4.x * ctw[8]  - p4.y * stw[8];
        s += p4.z * ctw[9]  - p4.w * stw[9];
        s += p5.x * ctw[10] - p5.y * stw[10];
        s += p5.z * ctw[11] - p5.w * stw[11];
        orow[w * 64 + d] = s;
    }
}

// ---------------------------------------------------------------------------
extern "C" void kernel_launch(void* const* d_in, const int* in_sizes, int n_in,
                              void* d_out, int out_size, void* d_ws, size_t ws_size,
                              hipStream_t stream) {
    const float* x    = (const float*)d_in[0];
    const float* w1re = (const float*)d_in[1];
    const float* w1im = (const float*)d_in[2];
    const float* w2re = (const float*)d_in[3];
    const float* w2im = (const float*)d_in[4];
    const float* w3re = (const float*)d_in[5];
    const float* w3im = (const float*)d_in[6];
    const float* w4re = (const float*)d_in[7];
    const float* w4im = (const float*)d_in[8];
    const float* mw1  = (const float*)d_in[9];
    const float* mb1  = (const float*)d_in[10];
    const float* mw2  = (const float*)d_in[11];
    const float* mb2  = (const float*)d_in[12];
    const float* cs   = (const float*)d_in[13];
    float* out = (float*)d_out;

    char* ws = (char*)d_ws;
    float2* X2   = (float2*)(ws);                 // 18,874,368 B  (reused as Y1)
    float2* X3   = (float2*)(ws + 18874368);      //  7,077,888 B
    float2* F    = (float2*)(ws + 25952256);      //  7,077,888 B
    float*  cft  = (float*) (ws + 33030144);      //    589,824 B
    float*  corr = (float*) (ws + 33619968);      //     32,768 B
    float2* Y1   = X2;                            // X2 dead after k_fwd_x

    hipLaunchKernelGGL(k_fwd_zy, dim3(8192), dim3(256), 0, stream, x, X2);
    hipLaunchKernelGGL(k_fwd_x,  dim3(3072), dim3(256), 0, stream, X2, X3);
    hipLaunchKernelGGL(k_mix,    dim3(576),  dim3(384), 0, stream, X3, F,
                       w1re, w1im, w2re, w2im, w3re, w3im, w4re, w4im);
    hipLaunchKernelGGL(k_inv_x,  dim3(3072), dim3(256), 0, stream, F, Y1);
    hipLaunchKernelGGL(k_cft,    dim3(128),  dim3(256), 0, stream, x, cft);
    hipLaunchKernelGGL(k_mlp,    dim3(256),  dim3(128), 0, stream,
                       cft, mw1, mb1, mw2, mb2, cs, corr);
    hipLaunchKernelGGL(k_inv_yz, dim3(8192), dim3(256), 0, stream, Y1, corr, out);
}

// Round 6
// 449.691 us; speedup vs baseline: 1.0667x; 1.0667x over previous
//
#include <hip/hip_runtime.h>
#include <math.h>

// ---------------------------------------------------------------------------
// SpectralConv3d + Chebyshev-Fourier correction, fp32, pruned separable DFTs.
// B=4, C=O=32, H=W=D=64. Modes: kx in {0..11, 52..63} (24), ky same (24),
// kz in {0..11} (12).
// out = (1/64^3) * Re[ sum F[kx,ky,kz] * w^(kx h + ky w + kz d) * c_kz ]
//       + corr_scale * corr[b,o,d],  c_0 = 1, c_kz = 2 (kz>=1).
//
// R1-R2: DFT symmetries + E/O pairing on all axes.
// R3: twiddle recurrences replace LDS twiddle gathers.
// R4: literal-twiddle z-stage, 4-wave structure: 92.5us, latency-bound.
// R5: b128-everything attempt: bank conflicts 6.3M->15.9M, regressed.
// R6 (this round): k_fwd_zy as SINGLE-WAVE blocks (64 thr), no staging:
//  - lane = w loads its 64-float row DIRECT from global (16 dwordx4, L1),
//  - computes ALL 12 kz in registers with fully-literal twiddles (no CMUL),
//  - dual-copy zA/zB handoff (24 b64 writes), b128 ystage_pair x3 passes,
//  - ONE barrier, ~12.7KB LDS, ~4 waves/SIMD.
// ---------------------------------------------------------------------------

#define CMUL_STEP(t, u) do { float _nx = (t).x*(u).x - (t).y*(u).y; \
    (t).y = (t).x*(u).y + (t).y*(u).x; (t).x = _nx; } while (0)

// cos(2*pi*m/64), m = 0..63 (sin(m) = cos((m+48)&63))
constexpr float TW_C[64] = {
     1.000000000000000f,  0.995184726672197f,  0.980785280403230f,  0.956940335732209f,
     0.923879532511287f,  0.881921264348355f,  0.831469612302545f,  0.773010453362737f,
     0.707106781186548f,  0.634393284163645f,  0.555570233019602f,  0.471396736825998f,
     0.382683432365090f,  0.290284677254462f,  0.195090322016128f,  0.098017140329561f,
     0.000000000000000f, -0.098017140329561f, -0.195090322016128f, -0.290284677254462f,
    -0.382683432365090f, -0.471396736825998f, -0.555570233019602f, -0.634393284163645f,
    -0.707106781186548f, -0.773010453362737f, -0.831469612302545f, -0.881921264348355f,
    -0.923879532511287f, -0.956940335732209f, -0.980785280403230f, -0.995184726672197f,
    -1.000000000000000f, -0.995184726672197f, -0.980785280403230f, -0.956940335732209f,
    -0.923879532511287f, -0.881921264348355f, -0.831469612302545f, -0.773010453362737f,
    -0.707106781186548f, -0.634393284163645f, -0.555570233019602f, -0.471396736825998f,
    -0.382683432365090f, -0.290284677254462f, -0.195090322016128f, -0.098017140329561f,
     0.000000000000000f,  0.098017140329561f,  0.195090322016128f,  0.290284677254462f,
     0.382683432365090f,  0.471396736825998f,  0.555570233019602f,  0.634393284163645f,
     0.707106781186548f,  0.773010453362737f,  0.831469612302545f,  0.881921264348355f,
     0.923879532511287f,  0.956940335732209f,  0.980785280403230f,  0.995184726672197f
};
constexpr float twc(int m) { return TW_C[m & 63]; }
constexpr float tws(int m) { return TW_C[(m + 48) & 63]; }

static __device__ __forceinline__ void fill_tw(float2* tw, int tid, int nthr) {
    // tw[m] = (cos(2 pi m / 64), sin(2 pi m / 64))
    for (int m = tid; m < 64; m += nthr) {
        float s, c;
        sincosf((float)m * 0.09817477042468103f, &s, &c);
        tw[m] = make_float2(c, s);
    }
}

// ---------------------------------------------------------------------------
// Shared y-stage inner loop: forward DFT over 64 samples -> conjugate output
// pair (k=ap, k=64-ap) with summation pairing w<->64-w via dual-copy LDS.
// Ar[w] = z[w] (w=0..63), Br[w] = z[64-w] (w=1..63). All b128 reads.
// ---------------------------------------------------------------------------
static __device__ __forceinline__ void ystage_pair(const float2* __restrict__ Ar,
                                                   const float2* __restrict__ Br,
                                                   int ap, float2& A, float2& Bc) {
    const float2 zw0 = Ar[0];
    const float2 zw32 = Ar[32];
    const float sg = (ap & 1) ? -1.f : 1.f;
    A.x = zw0.x + sg * zw32.x;  A.y = zw0.y + sg * zw32.y;
    Bc = A;
    float s_, c_;
    sincosf((float)ap * 0.09817477042468103f, &s_, &c_);
    const float2 u = make_float2(c_, s_);
    float2 t = u;                        // t = W^ap (w = 1)
    {   // w = 1
        float2 za = Ar[1], zb = Br[1];
        float Ex = za.x + zb.x, Ey = za.y + zb.y;
        float Ox = za.x - zb.x, Oy = za.y - zb.y;
        A.x  += t.x * Ex + t.y * Oy;  A.y  += t.x * Ey - t.y * Ox;
        Bc.x += t.x * Ex - t.y * Oy;  Bc.y += t.x * Ey + t.y * Ox;
    }
    #pragma unroll
    for (int w = 2; w < 32; w += 2) {
        CMUL_STEP(t, u);                       // t = W^{ap*w}
        const float4 a4 = *(const float4*)(Ar + w);  // z[w], z[w+1]
        const float4 b4 = *(const float4*)(Br + w);  // z[64-w], z[63-w]
        {
            float Ex = a4.x + b4.x, Ey = a4.y + b4.y;
            float Ox = a4.x - b4.x, Oy = a4.y - b4.y;
            A.x  += t.x * Ex + t.y * Oy;  A.y  += t.x * Ey - t.y * Ox;
            Bc.x += t.x * Ex - t.y * Oy;  Bc.y += t.x * Ey + t.y * Ox;
        }
        CMUL_STEP(t, u);                       // t = W^{ap*(w+1)}
        {
            float Ex = a4.z + b4.z, Ey = a4.w + b4.w;
            float Ox = a4.z - b4.z, Oy = a4.w - b4.w;
            A.x  += t.x * Ex + t.y * Oy;  A.y  += t.x * Ey - t.y * Ox;
            Bc.x += t.x * Ex - t.y * Oy;  Bc.y += t.x * Ey + t.y * Ox;
        }
    }
}

// ---------------------------------------------------------------------------
// Kernel 1: fused forward DFT along D (64->12) and W (64->24).
// grid = B*C*H = 8192 blocks, 64 threads (ONE wave). Lane = w.
// Row loaded direct from global into registers; all 12 kz accumulated with
// compile-time-literal twiddles; dual-copy zA/zB handoff; 3-pass y-stage.
// X2[(bc*64+h)*288 + a*12 + kz]
// ---------------------------------------------------------------------------
__global__ __launch_bounds__(64) void k_fwd_zy(const float* __restrict__ x,
                                               float2* __restrict__ X2) {
    __shared__ __align__(16) float2 zA[12 * 66];   // [kz][w]
    __shared__ __align__(16) float2 zB[12 * 66];   // [kz][64-w]
    const int w = threadIdx.x;           // 0..63
    const int blk = blockIdx.x;          // (b*32+c)*64 + h
    const float4* row4 = (const float4*)(x + (size_t)blk * 4096 + (size_t)w * 64);
    float4 q[16];
    #pragma unroll
    for (int j = 0; j < 16; ++j) q[j] = row4[j];
    // z-DFT over d, real-input pairing d <-> 64-d, all twiddles literal.
    float ax[12], ay[12];
    {
        const float x0v = q[0].x, x32v = q[8].x;
        #pragma unroll
        for (int k = 0; k < 12; ++k) {
            ax[k] = x0v + ((k & 1) ? -x32v : x32v);
            ay[k] = 0.f;
        }
    }
#define QE(dd) ((dd) & 3) == 0 ? q[(dd) >> 2].x : ((dd) & 3) == 1 ? q[(dd) >> 2].y : \
               ((dd) & 3) == 2 ? q[(dd) >> 2].z : q[(dd) >> 2].w
    #pragma unroll
    for (int d = 1; d < 32; ++d) {
        const float xa = QE(d);
        const float xb = QE(64 - d);
        const float e = xa + xb, o = xa - xb;
        #pragma unroll
        for (int k = 0; k < 12; ++k) {
            ax[k] += e * twc(k * d);
            ay[k] -= o * tws(k * d);
        }
    }
#undef QE
    #pragma unroll
    for (int k = 0; k < 12; ++k) {
        float2 v = make_float2(ax[k], ay[k]);
        zA[k * 66 + w] = v;
        zB[k * 66 + (64 - w)] = v;       // w=0 lands in pad slot 64
    }
    __syncthreads();                     // single wave: essentially free
    // y-stage: 156 items = 13 ap * 12 kz, 3 passes over the wave.
    float2* xout = X2 + (size_t)blk * 288;
    #pragma unroll
    for (int base = 0; base < 156; base += 64) {
        const int item = base + w;
        if (item < 156) {
            const int ap = item / 12, kz = item - (item / 12) * 12;
            float2 A, Bc;
            ystage_pair(&zA[kz * 66], &zB[kz * 66], ap, A, Bc);
            if (ap <= 11) xout[ap * 12 + kz] = A;
            if (ap >= 1)  xout[(24 - ap) * 12 + kz] = Bc;
        }
    }
}

// ---------------------------------------------------------------------------
// Kernel 2: forward DFT along H (64->24), dual-copy transposed staging +
// shared b128 y-loop. grid = B*C*24 = 3072, 256 threads.
// X3[bc*6912 + ax*288 + ay*12 + kz]
// ---------------------------------------------------------------------------
__global__ __launch_bounds__(256) void k_fwd_x(const float2* __restrict__ X2,
                                               float2* __restrict__ X3) {
    __shared__ __align__(16) float2 s2A[12 * 66];  // [kz][h]
    __shared__ __align__(16) float2 s2B[12 * 66];  // [kz][64-h]
    const int tid = threadIdx.x;
    const int blk = blockIdx.x;
    const int ay = blk % 24, bc = blk / 24;
    const float2* src = X2 + (size_t)bc * (64 * 288) + ay * 12;
    for (int i4 = tid; i4 < 384; i4 += 256) {      // 64 rows * 6 float4
        int hh = i4 / 6, c4 = i4 - hh * 6;
        float4 v = ((const float4*)(src + (size_t)hh * 288))[c4];
        int kz = 2 * c4;
        s2A[kz * 66 + hh]            = make_float2(v.x, v.y);
        s2A[(kz + 1) * 66 + hh]      = make_float2(v.z, v.w);
        s2B[kz * 66 + (64 - hh)]     = make_float2(v.x, v.y);
        s2B[(kz + 1) * 66 + (64 - hh)] = make_float2(v.z, v.w);
    }
    __syncthreads();
    float2* dst = X3 + (size_t)bc * 6912 + ay * 12;
    if (tid < 156) {                     // 13 ap values * 12 kz
        const int ap = tid / 12, kz = tid - (tid / 12) * 12;
        float2 A, Bc;
        ystage_pair(&s2A[kz * 66], &s2B[kz * 66], ap, A, Bc);
        if (ap <= 11) dst[ap * 288 + kz] = A;
        if (ap >= 1)  dst[(24 - ap) * 288 + kz] = Bc;
    }
}

// ---------------------------------------------------------------------------
// Kernel 3: mode mixing F[b,o,m] = sum_i X3[b,i,m] * (wre + i wim)[i,o,m].
// grid = 24*24 = 576 blocks (one (ax,ay)), 384 threads = (o,kz).
// Weights streamed from global exactly once in total.
// ---------------------------------------------------------------------------
__global__ __launch_bounds__(384) void k_mix(const float2* __restrict__ X3,
                                             float2* __restrict__ F,
        const float* __restrict__ w1re, const float* __restrict__ w1im,
        const float* __restrict__ w2re, const float* __restrict__ w2im,
        const float* __restrict__ w3re, const float* __restrict__ w3im,
        const float* __restrict__ w4re, const float* __restrict__ w4im) {
    __shared__ float2 xs[128 * 12];      // [b*32+i][kz]
    const int tid = threadIdx.x;
    const int blk = blockIdx.x;
    const int ax = blk / 24, ay = blk % 24;
    const int cx = ax >= 12 ? 1 : 0, cy = ay >= 12 ? 1 : 0;
    const int m1 = ax - cx * 12, m2 = ay - cy * 12;
    const int sel = cx + cy * 2;         // 0:w1 (lo,lo) 1:w2 (hi,lo) 2:w3 (lo,hi) 3:w4
    const float* wre = sel == 0 ? w1re : sel == 1 ? w2re : sel == 2 ? w3re : w4re;
    const float* wim = sel == 0 ? w1im : sel == 1 ? w2im : sel == 2 ? w3im : w4im;
    const size_t moff = (size_t)ax * 288 + (size_t)ay * 12;
    for (int i = tid; i < 1536; i += 384) {
        int bi = i / 12, kz = i - bi * 12;
        xs[i] = X3[(size_t)bi * 6912 + moff + kz];
    }
    __syncthreads();
    const int o = tid / 12, kz = tid - (tid / 12) * 12;
    const int wbase = o * 1728 + m1 * 144 + m2 * 12 + kz;
    float2 A0 = make_float2(0.f, 0.f), A1 = A0, A2 = A0, A3 = A0;
    for (int i = 0; i < 32; ++i) {
        float wr = wre[i * 55296 + wbase];
        float wi = wim[i * 55296 + wbase];
        float2 x0 = xs[i * 12 + kz];
        float2 x1 = xs[(32 + i) * 12 + kz];
        float2 x2 = xs[(64 + i) * 12 + kz];
        float2 x3 = xs[(96 + i) * 12 + kz];
        A0.x += x0.x * wr - x0.y * wi; A0.y += x0.x * wi + x0.y * wr;
        A1.x += x1.x * wr - x1.y * wi; A1.y += x1.x * wi + x1.y * wr;
        A2.x += x2.x * wr - x2.y * wi; A2.y += x2.x * wi + x2.y * wr;
        A3.x += x3.x * wr - x3.y * wi; A3.y += x3.x * wi + x3.y * wr;
    }
    F[(size_t)(0 * 32 + o) * 6912 + moff + kz] = A0;
    F[(size_t)(1 * 32 + o) * 6912 + moff + kz] = A1;
    F[(size_t)(2 * 32 + o) * 6912 + moff + kz] = A2;
    F[(size_t)(3 * 32 + o) * 6912 + moff + kz] = A3;
}

// ---------------------------------------------------------------------------
// Kernel 4: inverse DFT along H (24->64): output pairing h <-> 64-h composed
// with input-mode pairing ax <-> 24-ax; twiddles by recurrence (t <- t*W^hp).
// grid = B*O*24 = 3072, 256 threads. Y1[(bo*64+h)*288 + ay*12 + kz]
// ---------------------------------------------------------------------------
__global__ __launch_bounds__(256) void k_inv_x(const float2* __restrict__ F,
                                               float2* __restrict__ Y1) {
    __shared__ __align__(16) float2 fs[24 * 12];
    __shared__ float2 tw[64];
    const int tid = threadIdx.x;
    const int blk = blockIdx.x;
    const int ay = blk % 24, bo = blk / 24;
    fill_tw(tw, tid, 256);
    const float2* src = F + (size_t)bo * 6912 + ay * 12;
    for (int i4 = tid; i4 < 144; i4 += 256) {      // 24 rows * 6 float4
        int ax = i4 / 6, c4 = i4 - ax * 6;
        ((float4*)&fs[ax * 12])[c4] = ((const float4*)(src + (size_t)ax * 288))[c4];
    }
    __syncthreads();
    float2* dst = Y1 + (size_t)bo * (64 * 288) + ay * 12;
    // hp in 0..32: A -> h=hp; Bc -> h=64-hp (hp in 1..31).
    for (int idx = tid; idx < 396; idx += 256) {   // 33 hp * 12 kz
        int hp = idx / 12, kz = idx - (idx / 12) * 12;
        float2 f0  = fs[kz];
        float2 f12 = fs[12 * 12 + kz];
        float2 t12 = tw[(52 * hp) & 63];
        float2 A, Bc;
        A.x  = f0.x + f12.x * t12.x - f12.y * t12.y;
        A.y  = f0.y + f12.x * t12.y + f12.y * t12.x;
        Bc.x = f0.x + f12.x * t12.x + f12.y * t12.y;
        Bc.y = f0.y + f12.y * t12.x - f12.x * t12.y;
        const float2 u = tw[hp];         // hp <= 32 < 64
        float2 t = u;                    // t(a=1) = W^hp
        for (int a = 1; a <= 11; ++a) {
            float2 fa = fs[a * 12 + kz];
            float2 fb = fs[(24 - a) * 12 + kz];
            float Ex = fa.x + fb.x, Ey = fa.y + fb.y;
            float Ox = fa.x - fb.x, Oy = fa.y - fb.y;
            A.x  += t.x * Ex - t.y * Oy;  A.y  += t.x * Ey + t.y * Ox;
            Bc.x += t.x * Ex + t.y * Oy;  Bc.y += t.x * Ey - t.y * Ox;
            CMUL_STEP(t, u);
        }
        dst[hp * 288 + kz] = A;
        if (hp >= 1 && hp <= 31) dst[(64 - hp) * 288 + kz] = Bc;
    }
}

// ---------------------------------------------------------------------------
// Kernel 5: CFT branch — segment-0 Chebyshev (T0,T1,T2) + 3-freq rDFT over W.
// grid = B*C = 128 blocks, 256 threads = (q=w-group)*64 + d.
// cft[(b*64+d)*576 + c*18 + k*6 + f*2 + {re,im}]
// ---------------------------------------------------------------------------
__global__ __launch_bounds__(256) void k_cft(const float* __restrict__ x,
                                             float* __restrict__ cft) {
    __shared__ float2 tw[64];
    __shared__ float red[3 * 64 * 18];
    const int tid = threadIdx.x;
    const int blk = blockIdx.x;          // b*32 + c
    const int d = tid & 63, q = tid >> 6;
    fill_tw(tw, tid, 256);
    __syncthreads();
    float aR[3][3] = {{0.f}}, aI[3][3] = {{0.f}};
    const float* xb = x + (size_t)blk * 262144;
    for (int wi = 0; wi < 16; ++wi) {
        const int w = q * 16 + wi;
        float c0 = 0.f, c1 = 0.f, c2 = 0.f;
        #pragma unroll
        for (int s = 0; s < 8; ++s) {
            float xv = xb[(size_t)(s * 64 + w) * 64 + d];
            float t = (2.0f * (float)s - 7.0f) * (1.0f / 7.0f);
            c0 += xv;
            c1 += xv * t;
            c2 += xv * (2.0f * t * t - 1.0f);
        }
        c0 *= 0.125f; c1 *= 0.125f; c2 *= 0.125f;
        #pragma unroll
        for (int f = 0; f < 3; ++f) {
            float2 t = tw[(f * w) & 63];
            aR[0][f] += c0 * t.x; aI[0][f] -= c0 * t.y;
            aR[1][f] += c1 * t.x; aI[1][f] -= c1 * t.y;
            aR[2][f] += c2 * t.x; aI[2][f] -= c2 * t.y;
        }
    }
    if (q > 0) {
        float* dst = &red[((q - 1) * 64 + d) * 18];
        #pragma unroll
        for (int k = 0; k < 3; ++k)
            #pragma unroll
            for (int f = 0; f < 3; ++f) {
                dst[k * 6 + f * 2]     = aR[k][f];
                dst[k * 6 + f * 2 + 1] = aI[k][f];
            }
    }
    __syncthreads();
    if (q == 0) {
        #pragma unroll
        for (int qq = 0; qq < 3; ++qq) {
            const float* sr = &red[(qq * 64 + d) * 18];
            #pragma unroll
            for (int k = 0; k < 3; ++k)
                #pragma unroll
                for (int f = 0; f < 3; ++f) {
                    aR[k][f] += sr[k * 6 + f * 2];
                    aI[k][f] += sr[k * 6 + f * 2 + 1];
                }
        }
        const int b = blk >> 5, c = blk & 31;
        float* dst = cft + (size_t)(b * 64 + d) * 576 + c * 18;
        #pragma unroll
        for (int k = 0; k < 3; ++k)
            #pragma unroll
            for (int f = 0; f < 3; ++f) {
                dst[k * 6 + f * 2]     = aR[k][f];
                dst[k * 6 + f * 2 + 1] = aI[k][f];
            }
    }
}

// ---------------------------------------------------------------------------
// Kernel 6: MLP 576->128 (exact GeLU) ->32, pre-scaled by corr_scale.
// grid = B*D = 256 rows, 128 threads. corr[(b*32+o)*64 + d]
// ---------------------------------------------------------------------------
__global__ __launch_bounds__(128) void k_mlp(const float* __restrict__ cft,
                                             const float* __restrict__ w1,
                                             const float* __restrict__ b1,
                                             const float* __restrict__ w2,
                                             const float* __restrict__ b2,
                                             const float* __restrict__ cs,
                                             float* __restrict__ corr) {
    __shared__ float row[576];
    __shared__ float hbuf[128];
    const int n = blockIdx.x;            // b*64 + d
    const int tid = threadIdx.x;
    for (int i = tid; i < 576; i += 128) row[i] = cft[(size_t)n * 576 + i];
    __syncthreads();
    float acc = b1[tid];
    #pragma unroll 8
    for (int k = 0; k < 576; ++k) acc += row[k] * w1[k * 128 + tid];
    hbuf[tid] = 0.5f * acc * (1.0f + erff(acc * 0.70710678118654752f));
    __syncthreads();
    if (tid < 32) {
        float a2 = b2[tid];
        #pragma unroll 8
        for (int k = 0; k < 128; ++k) a2 += hbuf[k] * w2[k * 32 + tid];
        const int b = n >> 6, d = n & 63;
        corr[(b * 32 + tid) * 64 + d] = a2 * cs[0];
    }
}

// ---------------------------------------------------------------------------
// Kernel 7: fused inverse DFT along W (24->64) and D (12->64, c2r with c_kz),
// + correction add. grid = B*O*H = 8192, 256 threads.
// Stage A: mode-pair E/O + twiddle recurrence. Stage B: float4 y2 reads.
// ---------------------------------------------------------------------------
__global__ __launch_bounds__(256) void k_inv_yz(const float2* __restrict__ Y1,
                                                const float* __restrict__ corr,
                                                float* __restrict__ out) {
    __shared__ __align__(16) float2 y1[288];       // [a][kz]
    __shared__ __align__(16) float2 y2[64 * 12];   // [w][kz]
    __shared__ float2 tw[64];
    __shared__ float corrl[64];
    const int tid = threadIdx.x;
    const int blk = blockIdx.x;          // (b*32+o)*64 + h
    const int bo = blk >> 6;
    fill_tw(tw, tid, 256);
    {
        const float4* src4 = (const float4*)(Y1 + (size_t)blk * 288);
        for (int i4 = tid; i4 < 144; i4 += 256) ((float4*)y1)[i4] = src4[i4];
    }
    if (tid < 64) corrl[tid] = corr[bo * 64 + tid];
    __syncthreads();
    // stage A: W inverse, e^{+i 2pi ky w / 64}; thread = (w, kz-triplet).
    {
        const int w = tid >> 2, kz0 = (tid & 3) * 3;
        float2 a0 = make_float2(0.f, 0.f), a1 = a0, a2 = a0;
        {   // a = 0, ky = 0, t = (1,0)
            float2 f0 = y1[kz0], f1 = y1[kz0 + 1], f2 = y1[kz0 + 2];
            a0.x += f0.x; a0.y += f0.y;
            a1.x += f1.x; a1.y += f1.y;
            a2.x += f2.x; a2.y += f2.y;
        }
        {   // a = 12, ky = 52
            float2 t = tw[(52 * w) & 63];
            float2 f0 = y1[144 + kz0], f1 = y1[144 + kz0 + 1], f2 = y1[144 + kz0 + 2];
            a0.x += f0.x * t.x - f0.y * t.y; a0.y += f0.x * t.y + f0.y * t.x;
            a1.x += f1.x * t.x - f1.y * t.y; a1.y += f1.x * t.y + f1.y * t.x;
            a2.x += f2.x * t.x - f2.y * t.y; a2.y += f2.x * t.y + f2.y * t.x;
        }
        const float2 u = tw[w];
        float2 t = u;                    // t(a=1) = W^w
        for (int a = 1; a <= 11; ++a) {
            const float2* fa = &y1[a * 12 + kz0];
            const float2* fb = &y1[(24 - a) * 12 + kz0];
            float2 p0 = fa[0], p1 = fa[1], p2 = fa[2];
            float2 q0 = fb[0], q1 = fb[1], q2 = fb[2];
            float Ex, Ey, Ox, Oy;
            Ex = p0.x + q0.x; Ey = p0.y + q0.y; Ox = p0.x - q0.x; Oy = p0.y - q0.y;
            a0.x += t.x * Ex - t.y * Oy; a0.y += t.x * Ey + t.y * Ox;
            Ex = p1.x + q1.x; Ey = p1.y + q1.y; Ox = p1.x - q1.x; Oy = p1.y - q1.y;
            a1.x += t.x * Ex - t.y * Oy; a1.y += t.x * Ey + t.y * Ox;
            Ex = p2.x + q2.x; Ey = p2.y + q2.y; Ox = p2.x - q2.x; Oy = p2.y - q2.y;
            a2.x += t.x * Ex - t.y * Oy; a2.y += t.x * Ey + t.y * Ox;
            CMUL_STEP(t, u);
        }
        y2[w * 12 + kz0]     = a0;
        y2[w * 12 + kz0 + 1] = a1;
        y2[w * 12 + kz0 + 2] = a2;
    }
    // per-thread fixed d: hoist the 12 D-twiddles (scaled) into registers
    float ctw[12], stw[12];
    const int d = tid & 63;
    #pragma unroll
    for (int kz = 0; kz < 12; ++kz) {
        float2 t = tw[(kz * d) & 63];
        float sc = (kz == 0 ? 1.0f : 2.0f) * (1.0f / 262144.0f);
        ctw[kz] = t.x * sc;
        stw[kz] = t.y * sc;
    }
    __syncthreads();
    const float cv = corrl[d];
    float* orow = out + (size_t)blk * 4096;
    const int wq = tid >> 6;
    for (int r = 0; r < 16; ++r) {
        int w = r * 4 + wq;
        const float4* yv = (const float4*)&y2[w * 12];   // 12 float2 = 6 float4
        float4 p0 = yv[0], p1 = yv[1], p2 = yv[2];
        float4 p3 = yv[3], p4 = yv[4], p5 = yv[5];
        float s = cv;
        s += p0.x * ctw[0]  - p0.y * stw[0];
        s += p0.z * ctw[1]  - p0.w * stw[1];
        s += p1.x * ctw[2]  - p1.y * stw[2];
        s += p1.z * ctw[3]  - p1.w * stw[3];
        s += p2.x * ctw[4]  - p2.y * stw[4];
        s += p2.z * ctw[5]  - p2.w * stw[5];
        s += p3.x * ctw[6]  - p3.y * stw[6];
        s += p3.z * ctw[7]  - p3.w * stw[7];
        s += p4.x * ctw[8]  - p4.y * stw[8];
        s += p4.z * ctw[9]  - p4.w * stw[9];
        s += p5.x * ctw[10] - p5.y * stw[10];
        s += p5.z * ctw[11] - p5.w * stw[11];
        orow[w * 64 + d] = s;
    }
}

// ---------------------------------------------------------------------------
extern "C" void kernel_launch(void* const* d_in, const int* in_sizes, int n_in,
                              void* d_out, int out_size, void* d_ws, size_t ws_size,
                              hipStream_t stream) {
    const float* x    = (const float*)d_in[0];
    const float* w1re = (const float*)d_in[1];
    const float* w1im = (const float*)d_in[2];
    const float* w2re = (const float*)d_in[3];
    const float* w2im = (const float*)d_in[4];
    const float* w3re = (const float*)d_in[5];
    const float* w3im = (const float*)d_in[6];
    const float* w4re = (const float*)d_in[7];
    const float* w4im = (const float*)d_in[8];
    const float* mw1  = (const float*)d_in[9];
    const float* mb1  = (const float*)d_in[10];
    const float* mw2  = (const float*)d_in[11];
    const float* mb2  = (const float*)d_in[12];
    const float* cs   = (const float*)d_in[13];
    float* out = (float*)d_out;

    char* ws = (char*)d_ws;
    float2* X2   = (float2*)(ws);                 // 18,874,368 B  (reused as Y1)
    float2* X3   = (float2*)(ws + 18874368);      //  7,077,888 B
    float2* F    = (float2*)(ws + 25952256);      //  7,077,888 B
    float*  cft  = (float*) (ws + 33030144);      //    589,824 B
    float*  corr = (float*) (ws + 33619968);      //     32,768 B
    float2* Y1   = X2;                            // X2 dead after k_fwd_x

    hipLaunchKernelGGL(k_fwd_zy, dim3(8192), dim3(64),  0, stream, x, X2);
    hipLaunchKernelGGL(k_fwd_x,  dim3(3072), dim3(256), 0, stream, X2, X3);
    hipLaunchKernelGGL(k_mix,    dim3(576),  dim3(384), 0, stream, X3, F,
                       w1re, w1im, w2re, w2im, w3re, w3im, w4re, w4im);
    hipLaunchKernelGGL(k_inv_x,  dim3(3072), dim3(256), 0, stream, F, Y1);
    hipLaunchKernelGGL(k_cft,    dim3(128),  dim3(256), 0, stream, x, cft);
    hipLaunchKernelGGL(k_mlp,    dim3(256),  dim3(128), 0, stream,
                       cft, mw1, mb1, mw2, mb2, cs, corr);
    hipLaunchKernelGGL(k_inv_yz, dim3(8192), dim3(256), 0, stream, Y1, corr, out);
}